// Round 4
// baseline (410.463 us; speedup 1.0000x reference)
//
#include <hip/hip_runtime.h>
#include <hip/hip_cooperative_groups.h>
#include <math.h>

namespace cg = cooperative_groups;

// RoutingCapsules — B=16, I=2048, K=64, J=64, D=32, 3 routing iters.
// Identities (u_hat never materialized):
//   s[b,j,d]  = sum_k W[j,d,k] y[b,j,k],    y[b,j,k]  = sum_i c[b,j,i] x[b,i,k]
//   uv[b,j,i] = sum_k x[b,i,k] wv[b,j,k],   wv[b,j,k] = sum_d W[j,d,k] v[b,j,d]
// Iter-1 c uniform -> y1 = ybar[b,k]. Logits linear in wv -> b2 = x·(wv1+wv2).
//
// R3 post-mortem: 512-block cooperative launch exceeded the runtime's
// max-cooperative-grid (occupancy accounting caps LDS at 64 KB/CU -> 1 block/CU
// -> max 256 blocks); launch silently failed, d_out stayed zero. This round:
// 256 blocks (one per CU), each owns TWO i-tiles; caps uses all 4 waves.

#define BB 16
#define II 2048
#define KK 64
#define JJ 64
#define DD 32
#define ITILE 64
#define NT 32    // i-tiles per batch
#define TPB 2    // i-tiles per block

__global__ __launch_bounds__(256) void fused_caps_kernel(
    const float* __restrict__ x, const float* __restrict__ W,
    float* __restrict__ out, float* __restrict__ ybarp,
    float* __restrict__ wv, float* __restrict__ ypart)
{
    cg::grid_group grid = cg::this_grid();
    const int b = blockIdx.x >> 4;   // batch  0..15
    const int p = blockIdx.x & 15;   // tile-pair / j-quad  0..15
    const int tid = threadIdx.x;
    const int w = tid >> 6;
    const int lane = tid & 63;

    __shared__ float x_smT[KK][ITILE + 1];   // [k][i] transposed        (16.6 KB)
    __shared__ float uv_sm[ITILE][JJ + 1];   // uv -> c                  (16.6 KB)
    __shared__ float wvs[JJ][68];            // wv tile, f4-aligned rows (17.4 KB)
    __shared__ float red[8][72];             // cross-wave reductions    ( 2.3 KB)
    __shared__ float y_sm[4][KK];            // caps y row per wave
    __shared__ float v_sm[4][DD];            // caps v per wave
    // total ~53.3 KB  (<= 64 KB per-workgroup limit; 1 block/CU)

    auto stage_x = [&](int t) {
        const float4* x4 = (const float4*)(x + ((size_t)b * II + (size_t)t * ITILE) * KK);
        #pragma unroll
        for (int idx = tid; idx < ITILE * KK / 4; idx += 256) {
            const int i = idx >> 4;
            const int kq = idx & 15;
            const float4 v = x4[idx];
            x_smT[kq * 4 + 0][i] = v.x;
            x_smT[kq * 4 + 1][i] = v.y;
            x_smT[kq * 4 + 2][i] = v.z;
            x_smT[kq * 4 + 3][i] = v.w;
        }
    };

    // ============ phase 0: ybar partials (also warms x into L3) ============
    #pragma unroll
    for (int tt = 0; tt < TPB; ++tt) {
        const int t = p * TPB + tt;
        stage_x(t);
        __syncthreads();
        float a = 0.f;   // wave w sums i-slice [16w,16w+16) for k=lane
        #pragma unroll
        for (int ii = w * 16; ii < w * 16 + 16; ++ii) a += x_smT[lane][ii];
        red[w][lane] = a;
        __syncthreads();
        if (w == 0)
            ybarp[(size_t)(b * NT + t) * KK + lane] =
                (red[0][lane] + red[1][lane] + red[2][lane] + red[3][lane]) * (1.0f / 64.0f);
        __syncthreads();   // before restaging x next iter
    }
    __threadfence();
    grid.sync();

    // ---- caps phase: wave w handles j = 4p + w ----
    // MODE 0: y=sum ybarp, wv=W^T v | MODE 1: y=sum ypart, wv+=W^T v | MODE 2: out
    auto caps_phase = [&](int MODE) {
        const int j = p * 4 + w;
        float a = 0.f;
        if (MODE == 0) {
            const float* yp = ybarp + (size_t)b * NT * KK + lane;
            #pragma unroll
            for (int t = 0; t < NT; ++t) a += yp[(size_t)t * KK];
        } else {
            const float* pp = ypart + ((size_t)b * NT * JJ + j) * KK + lane;
            #pragma unroll
            for (int t = 0; t < NT; ++t) a += pp[(size_t)t * JJ * KK];
        }
        y_sm[w][lane] = a;
        // s[d] = sum_k W[j,d,k] y[k]  (lane = d < 32; W row via float4 from L2)
        const float4* Wr4 = (const float4*)(W + (size_t)j * DD * KK);
        float sv = 0.f;
        if (lane < DD) {
            float acc = 0.f;
            #pragma unroll
            for (int q = 0; q < 16; ++q) {
                const float4 wq = Wr4[lane * 16 + q];
                acc += wq.x * y_sm[w][q * 4 + 0] + wq.y * y_sm[w][q * 4 + 1]
                     + wq.z * y_sm[w][q * 4 + 2] + wq.w * y_sm[w][q * 4 + 3];
            }
            sv = acc;
        }
        float ps = (lane < DD) ? sv * sv : 0.f;
        #pragma unroll
        for (int m = 1; m < 64; m <<= 1) ps += __shfl_xor(ps, m, 64);
        const float f = ps / ((1.f + ps) * (sqrtf(ps) + 1e-8f));   // squash factor
        if (MODE == 2) {
            if (lane < DD) out[((size_t)b * JJ + j) * DD + lane] = sv * f;
        } else {
            if (lane < DD) v_sm[w][lane] = sv * f;
            // wv[k] = sum_d W[j,d,k] v[d]  (lane = k; coalesced W reads)
            const float* Wj = W + (size_t)j * DD * KK + lane;
            float acc = 0.f;
            #pragma unroll
            for (int d = 0; d < DD; ++d) acc += Wj[d * KK] * v_sm[w][d];
            const size_t idx = ((size_t)b * JJ + j) * KK + lane;
            wv[idx] = (MODE == 1) ? acc + wv[idx] : acc;
        }
        __threadfence();
    };

    // ---- route phase: per tile: uv = x·wv^T, softmax_j, ypart = c^T·x ----
    auto route_phase = [&]() {
        const float4* wv4 = (const float4*)(wv + (size_t)b * JJ * KK);
        #pragma unroll
        for (int idx = tid; idx < JJ * KK / 4; idx += 256)
            *(float4*)&wvs[idx >> 4][(idx & 15) * 4] = wv4[idx];
        #pragma unroll
        for (int tt = 0; tt < TPB; ++tt) {
            const int t = p * TPB + tt;
            __syncthreads();   // prev tile's ypart reads of x_smT done (and wvs staged)
            stage_x(t);
            __syncthreads();
            // uv[i][j] = sum_k x[i][k] wv[j][k], 4i x 4j per thread
            {
                const int ib = (tid & 15) * 4, jb = (tid >> 4) * 4;
                float acc[4][4] = {};
                for (int k = 0; k < KK; ++k) {
                    float xv[4], wvv[4];
                    #pragma unroll
                    for (int c = 0; c < 4; ++c) xv[c] = x_smT[k][ib + c];
                    #pragma unroll
                    for (int r = 0; r < 4; ++r) wvv[r] = wvs[jb + r][k];
                    #pragma unroll
                    for (int c = 0; c < 4; ++c)
                        #pragma unroll
                        for (int r = 0; r < 4; ++r)
                            acc[c][r] += xv[c] * wvv[r];
                }
                #pragma unroll
                for (int c = 0; c < 4; ++c)
                    #pragma unroll
                    for (int r = 0; r < 4; ++r)
                        uv_sm[ib + c][jb + r] = acc[c][r];
            }
            __syncthreads();
            // softmax over j: wave w owns j-slice [16w,16w+16) of row i=lane
            {
                const int i = lane;
                const int j0 = w * 16;
                float m = -1e30f;
                #pragma unroll
                for (int jj = 0; jj < 16; ++jj) m = fmaxf(m, uv_sm[i][j0 + jj]);
                red[w][i] = m;
                __syncthreads();
                m = fmaxf(fmaxf(red[0][i], red[1][i]), fmaxf(red[2][i], red[3][i]));
                float s = 0.f;
                #pragma unroll
                for (int jj = 0; jj < 16; ++jj) {
                    const float e = __expf(uv_sm[i][j0 + jj] - m);
                    uv_sm[i][j0 + jj] = e;
                    s += e;
                }
                red[4 + w][i] = s;
                __syncthreads();
                const float inv = 1.f / (red[4][i] + red[5][i] + red[6][i] + red[7][i]);
                #pragma unroll
                for (int jj = 0; jj < 16; ++jj) uv_sm[i][j0 + jj] *= inv;   // now c[i][j]
            }
            __syncthreads();
            // ypart[t][j][k] = sum_i c[i][j] x[i][k], 4j x 4k per thread, float4 stores
            {
                const int jb = (tid & 15) * 4, kb = (tid >> 4) * 4;
                float acc[4][4] = {};
                for (int i = 0; i < ITILE; ++i) {
                    float cv[4], xv[4];
                    #pragma unroll
                    for (int r = 0; r < 4; ++r) cv[r] = uv_sm[i][jb + r];
                    #pragma unroll
                    for (int c = 0; c < 4; ++c) xv[c] = x_smT[kb + c][i];
                    #pragma unroll
                    for (int r = 0; r < 4; ++r)
                        #pragma unroll
                        for (int c = 0; c < 4; ++c)
                            acc[r][c] += cv[r] * xv[c];
                }
                float* yp = ypart + ((size_t)b * NT + t) * JJ * KK;
                #pragma unroll
                for (int r = 0; r < 4; ++r)
                    *(float4*)&yp[(jb + r) * KK + kb] =
                        make_float4(acc[r][0], acc[r][1], acc[r][2], acc[r][3]);
            }
        }
        __threadfence();
    };

    caps_phase(0);       // wv1
    grid.sync();
    route_phase();       // c2 -> y2 partials
    grid.sync();
    caps_phase(1);       // wv = wv1 + wv2
    grid.sync();
    route_phase();       // c3 -> y3 partials
    grid.sync();
    caps_phase(2);       // out = squash(s3)
}

// Workspace (floats): wv[65536] | ybarp[32768] | ypart[2097152]  (~8.8 MB)
extern "C" void kernel_launch(void* const* d_in, const int* in_sizes, int n_in,
                              void* d_out, int out_size, void* d_ws, size_t ws_size,
                              hipStream_t stream) {
    const float* x = (const float*)d_in[0];
    const float* W = (const float*)d_in[1];
    float* out = (float*)d_out;
    float* ws = (float*)d_ws;

    float* wv    = ws;                     // 65536
    float* ybarp = ws + 65536;             // 32768
    float* ypart = ws + 65536 + 32768;     // 2097152

    void* args[] = {(void*)&x, (void*)&W, (void*)&out,
                    (void*)&ybarp, (void*)&wv, (void*)&ypart};
    hipLaunchCooperativeKernel((void*)fused_caps_kernel, dim3(256), dim3(256),
                               args, 0, stream);
}

// Round 5
// 276.490 us; speedup vs baseline: 1.4845x; 1.4845x over previous
//
#include <hip/hip_runtime.h>
#include <math.h>

// RoutingCapsules — B=16, I=2048, K=64, J=64, D=32, 3 routing iters.
//   s[b,j,d]  = sum_k W[j,d,k] y[b,j,k],    y[b,j,k]  = sum_i c[b,j,i] x[b,i,k]
//   uv[b,j,i] = sum_k x[b,i,k] wv[b,j,k],   wv[b,j,k] = sum_d W[j,d,k] v[b,j,d]
// Iter-1 c uniform -> y1 = ybar[b,k]. Logits linear in wv -> b2 = x·(wv1+wv2).
//
// R4 post-mortem: CG grid.sync costs ~60 us each on MI355X (system-scope L2
// flush + 256-block spin). This round: 3 launches; the cheap "caps" stages run
// as a last-4-blocks-per-batch finisher inside the producing kernel
// (threadfence + per-batch ticket counter + agent-scope acquire spin).
// Max 4 spinners/batch (64 total) -> progress guaranteed under any dispatch order.

#define BB 16
#define II 2048
#define KK 64
#define JJ 64
#define DD 32
#define ITILE 64
#define NT 32    // i-tiles per batch (route)
#define CH 16    // ybar chunks per batch (K1)

// ---------------------------------------------------------------------------
// Straggler caps: this block handles j in [j0, j0+16) for batch b.
//  MODE 0: y = reduced ybarp (one row, all j)            -> dst = wv1
//  MODE 1: y[j] = sum_t ypart; wv2 + wvs(LDS wv1)        -> dst = wvT
//  MODE 2: y[j] = sum_t ypart; v written directly        -> dst = out
// ---------------------------------------------------------------------------
template <int MODE>
__device__ void caps_tail(const float* __restrict__ W,
                          const float* __restrict__ ysrc,
                          const float (*wvs)[68],
                          float* __restrict__ dst,
                          float* __restrict__ y_sm,   // >= 16*68 floats
                          float* __restrict__ v_sm,   // >= 16*34 floats
                          int b, int j0, int tid)
{
    // (a) gather y rows
    if (MODE == 0) {
        if (tid < KK) {
            float a = 0.f;
            #pragma unroll
            for (int q = 0; q < CH; ++q) a += ysrc[(size_t)(b * CH + q) * KK + tid];
            y_sm[tid] = a;
        }
    } else {
        const int k = tid & 63, jj = tid >> 6;
        #pragma unroll
        for (int l = jj; l < 16; l += 4) {
            const float* p = ysrc + ((size_t)b * NT * JJ + (j0 + l)) * KK + k;
            float a = 0.f;
            #pragma unroll 8
            for (int tt = 0; tt < NT; ++tt) a += p[(size_t)tt * JJ * KK];
            y_sm[l * 68 + k] = a;
        }
    }
    __syncthreads();

    // (b) s[j,d] = W[j,d,:]·y[j,:]; squash; v   (thread: d=tid&31, covers 2 j's)
    {
        const int d = tid & 31, jh = tid >> 5;   // jh 0..7
        #pragma unroll
        for (int h = 0; h < 2; ++h) {
            const int l = jh + h * 8;
            const int j = j0 + l;
            const float* yrow = (MODE == 0) ? y_sm : (y_sm + l * 68);
            const float4* Wr = (const float4*)(W + ((size_t)j * DD + d) * KK);
            float acc = 0.f;
            #pragma unroll
            for (int q = 0; q < 16; ++q) {
                const float4 wq = Wr[q];
                acc += wq.x * yrow[q * 4 + 0] + wq.y * yrow[q * 4 + 1]
                     + wq.z * yrow[q * 4 + 2] + wq.w * yrow[q * 4 + 3];
            }
            float ps = acc * acc;   // reduce over d: masks 1..16 stay in 32-lane half
            #pragma unroll
            for (int m = 1; m < 32; m <<= 1) ps += __shfl_xor(ps, m, 64);
            const float f = ps / ((1.f + ps) * (sqrtf(ps) + 1e-8f));
            const float v = acc * f;
            if (MODE == 2) dst[((size_t)b * JJ + j) * DD + d] = v;
            else           v_sm[l * 34 + d] = v;
        }
    }
    if (MODE == 2) return;
    __syncthreads();

    // (c) wv[j][k] = sum_d W[j,d,k] v[j,d]  (+ wv1 from LDS for MODE 1)
    {
        const int k = tid & 63, jj = tid >> 6;
        #pragma unroll
        for (int l = jj; l < 16; l += 4) {
            const int j = j0 + l;
            const float* Wj = W + (size_t)j * DD * KK + k;
            const float* vr = v_sm + l * 34;
            float acc = 0.f;
            #pragma unroll
            for (int d = 0; d < DD; ++d) acc += Wj[d * KK] * vr[d];
            if (MODE == 1) acc += wvs[j][k];
            dst[((size_t)b * JJ + j) * KK + k] = acc;
        }
    }
}

// ---------------------------------------------------------------------------
// K1: ybar partials (grid 16x16); last-4 blocks per batch compute wv1.
// ---------------------------------------------------------------------------
__global__ __launch_bounds__(256) void ybar_caps_kernel(
    const float* __restrict__ x, const float* __restrict__ W,
    float* __restrict__ ybarp, float* __restrict__ wv1, int* __restrict__ cnt)
{
    const int b = blockIdx.x >> 4;
    const int q = blockIdx.x & 15;
    const int tid = threadIdx.x;
    __shared__ float sm[256];
    __shared__ float y_sm[16 * 68];
    __shared__ float v_sm[16 * 34];
    __shared__ int ticket_sm;

    {
        const int k = tid & 63, r = tid >> 6;
        const float* xp = x + ((size_t)b * II + (size_t)q * 128) * KK + k;
        float acc = 0.f;
        #pragma unroll 8
        for (int i = r; i < 128; i += 4) acc += xp[(size_t)i * KK];
        sm[tid] = acc;
        __syncthreads();
        if (tid < 64)
            ybarp[(size_t)(b * CH + q) * KK + tid] =
                (sm[tid] + sm[tid + 64] + sm[tid + 128] + sm[tid + 192]) * (1.0f / 64.0f);
    }
    __threadfence();                       // release ybarp stores (agent scope)
    __syncthreads();
    if (tid == 0) ticket_sm = atomicAdd(&cnt[b * 32], 1);
    __syncthreads();
    const int ticket = ticket_sm;
    if (ticket < CH - 4) return;           // non-stragglers exit
    if (tid == 0) {
        while (__hip_atomic_load(&cnt[b * 32], __ATOMIC_ACQUIRE,
                                 __HIP_MEMORY_SCOPE_AGENT) < CH)
            __builtin_amdgcn_s_sleep(2);
    }
    __syncthreads();
    caps_tail<0>(W, ybarp, nullptr, wv1, y_sm, v_sm, b, (ticket - (CH - 4)) * 16, tid);
}

// ---------------------------------------------------------------------------
// K2/K3: route pass (grid 16x32): uv = x·wv^T, softmax_j, ypart = c^T·x.
// Last-4 blocks per batch run caps: PASS=1 -> wvT = wv1+wv2; PASS=2 -> out.
// ---------------------------------------------------------------------------
template <int PASS>
__global__ __launch_bounds__(256) void route_fused(
    const float* __restrict__ x, const float* __restrict__ W,
    const float* __restrict__ wvsrc, float* __restrict__ ypart,
    float* __restrict__ dst, int* __restrict__ cnt)
{
    const int b = blockIdx.x >> 5;
    const int t = blockIdx.x & 31;
    const int tid = threadIdx.x;
    const int i0 = t * ITILE;

    __shared__ float x_smT[KK][ITILE + 1];  // [k][i] transposed
    __shared__ float wvs[JJ][68];           // wv tile (f4-aligned rows)
    __shared__ float uv_sm[ITILE][JJ + 1];  // uv -> c ; reused as y_sm in tail
    __shared__ float red[8][72];            // softmax cross-wave ; reused as v_sm
    __shared__ int ticket_sm;

    // stage wv + x tile
    const float4* wv4 = (const float4*)(wvsrc + (size_t)b * JJ * KK);
    #pragma unroll
    for (int idx = tid; idx < JJ * KK / 4; idx += 256)
        *(float4*)&wvs[idx >> 4][(idx & 15) * 4] = wv4[idx];
    const float4* x4 = (const float4*)(x + ((size_t)b * II + i0) * KK);
    #pragma unroll
    for (int idx = tid; idx < ITILE * KK / 4; idx += 256) {
        const int i = idx >> 4;
        const int kq = idx & 15;
        const float4 v = x4[idx];
        x_smT[kq * 4 + 0][i] = v.x;
        x_smT[kq * 4 + 1][i] = v.y;
        x_smT[kq * 4 + 2][i] = v.z;
        x_smT[kq * 4 + 3][i] = v.w;
    }
    __syncthreads();

    // uv[i][j] = sum_k x[i][k] wv[j][k], 4i x 4j per thread
    {
        const int ib = (tid & 15) * 4, jb = (tid >> 4) * 4;
        float acc[4][4] = {};
        for (int k = 0; k < KK; ++k) {
            float xv[4], wvv[4];
            #pragma unroll
            for (int c = 0; c < 4; ++c) xv[c] = x_smT[k][ib + c];
            #pragma unroll
            for (int r = 0; r < 4; ++r) wvv[r] = wvs[jb + r][k];
            #pragma unroll
            for (int c = 0; c < 4; ++c)
                #pragma unroll
                for (int r = 0; r < 4; ++r)
                    acc[c][r] += xv[c] * wvv[r];
        }
        #pragma unroll
        for (int c = 0; c < 4; ++c)
            #pragma unroll
            for (int r = 0; r < 4; ++r)
                uv_sm[ib + c][jb + r] = acc[c][r];
    }
    __syncthreads();

    // softmax over j: wave w owns j-slice [16w,16w+16) of row i=lane
    {
        const int i = tid & 63;
        const int w = tid >> 6;
        const int j0 = w * 16;
        float m = -1e30f;
        #pragma unroll
        for (int jj = 0; jj < 16; ++jj) m = fmaxf(m, uv_sm[i][j0 + jj]);
        red[w][i] = m;
        __syncthreads();
        m = fmaxf(fmaxf(red[0][i], red[1][i]), fmaxf(red[2][i], red[3][i]));
        float s = 0.f;
        #pragma unroll
        for (int jj = 0; jj < 16; ++jj) {
            const float e = __expf(uv_sm[i][j0 + jj] - m);
            uv_sm[i][j0 + jj] = e;
            s += e;
        }
        red[4 + w][i] = s;
        __syncthreads();
        const float inv = 1.f / (red[4][i] + red[5][i] + red[6][i] + red[7][i]);
        #pragma unroll
        for (int jj = 0; jj < 16; ++jj) uv_sm[i][j0 + jj] *= inv;   // now c[i][j]
    }
    __syncthreads();

    // ypart[b][t][j][k] = sum_i c[i][j] x[i][k], 4j x 4k per thread
    {
        const int jb = (tid & 15) * 4, kb = (tid >> 4) * 4;
        float acc[4][4] = {};
        for (int i = 0; i < ITILE; ++i) {
            float cv[4], xv[4];
            #pragma unroll
            for (int r = 0; r < 4; ++r) cv[r] = uv_sm[i][jb + r];
            #pragma unroll
            for (int c = 0; c < 4; ++c) xv[c] = x_smT[kb + c][i];
            #pragma unroll
            for (int r = 0; r < 4; ++r)
                #pragma unroll
                for (int c = 0; c < 4; ++c)
                    acc[r][c] += cv[r] * xv[c];
        }
        float* yp = ypart + ((size_t)b * NT + t) * JJ * KK;
        #pragma unroll
        for (int r = 0; r < 4; ++r)
            *(float4*)&yp[(jb + r) * KK + kb] =
                make_float4(acc[r][0], acc[r][1], acc[r][2], acc[r][3]);
    }

    __threadfence();                       // release ypart stores (agent scope)
    __syncthreads();
    if (tid == 0) ticket_sm = atomicAdd(&cnt[b * 32], 1);
    __syncthreads();
    const int ticket = ticket_sm;
    if (ticket < NT - 4) return;           // non-stragglers exit
    if (tid == 0) {
        while (__hip_atomic_load(&cnt[b * 32], __ATOMIC_ACQUIRE,
                                 __HIP_MEMORY_SCOPE_AGENT) < NT)
            __builtin_amdgcn_s_sleep(2);
    }
    __syncthreads();
    caps_tail<PASS>(W, ypart, (PASS == 1) ? wvs : nullptr, dst,
                    (float*)uv_sm, (float*)red, b, (ticket - (NT - 4)) * 16, tid);
}

// ---------------------------------------------------------------------------
// Workspace: cnt int[1536] (3 x 16 batches x 32-int stride) |
//            ybarp f[16384] | wv1 f[65536] | wvT f[65536] | ypart f[2097152]
// ---------------------------------------------------------------------------
extern "C" void kernel_launch(void* const* d_in, const int* in_sizes, int n_in,
                              void* d_out, int out_size, void* d_ws, size_t ws_size,
                              hipStream_t stream) {
    const float* x = (const float*)d_in[0];
    const float* W = (const float*)d_in[1];
    float* out = (float*)d_out;

    int* cnt = (int*)d_ws;                        // 1536 ints (6 KB)
    float* fbase = (float*)d_ws + 1536;
    float* ybarp = fbase;                         // 16384
    float* wv1   = ybarp + 16384;                 // 65536
    float* wvT   = wv1 + 65536;                   // 65536
    float* ypart = wvT + 65536;                   // 2097152

    hipMemsetAsync(cnt, 0, 1536 * sizeof(int), stream);
    ybar_caps_kernel<<<dim3(BB * CH), 256, 0, stream>>>(x, W, ybarp, wv1, cnt);
    route_fused<1><<<dim3(BB * NT), 256, 0, stream>>>(x, W, wv1, ypart, wvT, cnt + 512);
    route_fused<2><<<dim3(BB * NT), 256, 0, stream>>>(x, W, wvT, ypart, out, cnt + 1024);
}

// Round 6
// 164.810 us; speedup vs baseline: 2.4905x; 1.6776x over previous
//
#include <hip/hip_runtime.h>
#include <math.h>

// RoutingCapsules — B=16, I=2048, K=64, J=64, D=32, 3 routing iters.
//   s[b,j,d]  = sum_k W[j,d,k] y[b,j,k],    y[b,j,k]  = sum_i c[b,j,i] x[b,i,k]
//   uv[b,j,i] = sum_k x[b,i,k] wv[b,j,k],   wv[b,j,k] = sum_d W[j,d,k] v[b,j,d]
// Iter-1 c uniform -> y1 = ybar[b,k]. Logits linear in wv:
//   b2 = uv1+uv2 = x·(wv1+wv2) = x·(W^T (v1+v2)).
//
// R4/R5 post-mortem: intra-kernel cross-block sync is poison on MI355X
// (grid.sync ~60us; agent-acquire spin loops cause an L2-invalidate storm ->
// 110us kernels at 5% VALUBusy). This round: 4 plain launches, no atomics, no
// fences. Route blocks redundantly compute their caps inputs from L2-resident
// W (512 KB) — cheaper than an extra launch + ~8us gap.

#define BB 16
#define II 2048
#define KK 64
#define JJ 64
#define DD 32
#define ITILE 64
#define HB 16      // route blocks per batch (2 i-tiles each)
#define NP 16      // ypart partials per batch
#define YQ 8       // ybar chunks per batch

// ---------------------------------------------------------------------------
// K1: ybar partials. grid 128 = (b, q of 256 i). ybarp[b,q,k].
// ---------------------------------------------------------------------------
__global__ __launch_bounds__(256) void ybar_kernel(const float* __restrict__ x,
                                                   float* __restrict__ ybarp) {
    const int b = blockIdx.x >> 3, q = blockIdx.x & 7;
    const int tid = threadIdx.x, k = tid & 63, r = tid >> 6;
    const float* xp = x + ((size_t)b * II + q * 256) * KK + k;
    float acc = 0.f;
    #pragma unroll 8
    for (int i = r; i < 256; i += 4) acc += xp[(size_t)i * KK];
    __shared__ float sm[256];
    sm[tid] = acc;
    __syncthreads();
    if (tid < 64)
        ybarp[(b * YQ + q) * KK + tid] =
            (sm[tid] + sm[tid + 64] + sm[tid + 128] + sm[tid + 192]) * (1.f / 64.f);
}

// ---------------------------------------------------------------------------
// K2 (PASS=1) / K3 (PASS=2): self-caps + route. grid 256 = (b, h), 2 tiles/block.
//  PASS1: v = squash(W·ybar)           (h==0 publishes v1g); wv = W^T v
//  PASS2: y2 = reduce(ypin); v = squash(W·y2) + v1g;         wv = W^T v
//  Then per tile: uv = x·wv^T, softmax_j -> c, yacc += c^T·x (regs), store ypout.
// ---------------------------------------------------------------------------
template <int PASS>
__global__ __launch_bounds__(256) void route_caps(
    const float* __restrict__ x, const float* __restrict__ W,
    const float* __restrict__ ybarp, const float* __restrict__ ypin,
    float* __restrict__ v1g, float* __restrict__ ypout)
{
    const int b = blockIdx.x >> 4;
    const int h = blockIdx.x & 15;
    const int tid = threadIdx.x;

    __shared__ float x_smT[KK][ITILE + 1];   // [k][i] transposed      (16.6 KB)
    __shared__ float buf[ITILE * 68];        // uv view [i*65+j] / y2 view [j*68+k] (17.4 KB)
    __shared__ float wvs[JJ][68];            // wv tile                (17.4 KB)
    __shared__ float red[8][72];             // softmax cross-wave     ( 2.3 KB)
    __shared__ float v_sm[JJ][33];           // v per j                ( 8.4 KB)
    __shared__ float ybar_sm[KK];
    // ~62.5 KB -> 1 block/CU, grid 256 = full machine

    const int j = tid >> 2;     // caps: each thread owns (j, 8 d's)
    const int dq = tid & 3;

    // ---------------- caps: v_sm[j][d] ----------------
    if (PASS == 1) {
        if (tid < KK) {
            float a = 0.f;
            #pragma unroll
            for (int q = 0; q < YQ; ++q) a += ybarp[(b * YQ + q) * KK + tid];
            ybar_sm[tid] = a;
        }
        __syncthreads();
        const float4* Wj4 = (const float4*)(W + ((size_t)j * DD + dq * 8) * KK);
        float sv[8]; float ss = 0.f;
        #pragma unroll
        for (int dd = 0; dd < 8; ++dd) {
            float a = 0.f;
            #pragma unroll
            for (int q = 0; q < 16; ++q) {
                const float4 wq = Wj4[dd * 16 + q];
                a += wq.x * ybar_sm[q * 4 + 0] + wq.y * ybar_sm[q * 4 + 1]
                   + wq.z * ybar_sm[q * 4 + 2] + wq.w * ybar_sm[q * 4 + 3];
            }
            sv[dd] = a; ss += a * a;
        }
        ss += __shfl_xor(ss, 1); ss += __shfl_xor(ss, 2);   // quad shares j
        const float f = ss / ((1.f + ss) * (sqrtf(ss) + 1e-8f));
        #pragma unroll
        for (int dd = 0; dd < 8; ++dd) {
            const float v = sv[dd] * f;
            v_sm[j][dq * 8 + dd] = v;
            if (h == 0) v1g[((size_t)b * JJ + j) * DD + dq * 8 + dd] = v;
        }
    } else {
        // y2[j][k] = sum_p ypin[b,p,j,k]  (coalesced: lanes = consecutive k)
        for (int e = tid; e < JJ * KK; e += 256) {
            const int jj = e >> 6, k = e & 63;
            const float* p = ypin + ((size_t)(b * NP) * JJ + jj) * KK + k;
            float a = 0.f;
            #pragma unroll
            for (int pp = 0; pp < NP; ++pp) a += p[(size_t)pp * JJ * KK];
            buf[jj * 68 + k] = a;
        }
        __syncthreads();
        const float4* Wj4 = (const float4*)(W + ((size_t)j * DD + dq * 8) * KK);
        const float4* yr = (const float4*)&buf[j * 68];
        float sv[8]; float ss = 0.f;
        #pragma unroll
        for (int dd = 0; dd < 8; ++dd) {
            float a = 0.f;
            #pragma unroll
            for (int q = 0; q < 16; ++q) {
                const float4 wq = Wj4[dd * 16 + q];
                const float4 yq = yr[q];
                a += wq.x * yq.x + wq.y * yq.y + wq.z * yq.z + wq.w * yq.w;
            }
            sv[dd] = a; ss += a * a;
        }
        ss += __shfl_xor(ss, 1); ss += __shfl_xor(ss, 2);
        const float f = ss / ((1.f + ss) * (sqrtf(ss) + 1e-8f));
        #pragma unroll
        for (int dd = 0; dd < 8; ++dd)
            v_sm[j][dq * 8 + dd] =
                sv[dd] * f + v1g[((size_t)b * JJ + j) * DD + dq * 8 + dd];
    }
    __syncthreads();

    // ---------------- wv: wvs[j][k] = sum_d W[j,d,k] v[j,d] ----------------
    {
        const int kq = tid & 3;   // 16-k slab
        const float* Wj = W + (size_t)j * DD * KK + kq * 16;
        float acc[16] = {};
        for (int d = 0; d < DD; ++d) {
            const float vd = v_sm[j][d];
            const float4* Wr = (const float4*)(Wj + d * KK);
            #pragma unroll
            for (int m = 0; m < 4; ++m) {
                const float4 wq = Wr[m];
                acc[m * 4 + 0] += wq.x * vd; acc[m * 4 + 1] += wq.y * vd;
                acc[m * 4 + 2] += wq.z * vd; acc[m * 4 + 3] += wq.w * vd;
            }
        }
        #pragma unroll
        for (int m = 0; m < 4; ++m)
            *(float4*)&wvs[j][kq * 16 + m * 4] =
                make_float4(acc[m*4], acc[m*4+1], acc[m*4+2], acc[m*4+3]);
    }
    __syncthreads();

    // ---------------- route: 2 tiles, ypart accumulated in registers ----------------
    float yacc[4][4] = {};
    const int jb = (tid & 15) * 4, kb = (tid >> 4) * 4;    // ypart mapping
    const int ib = (tid & 15) * 4, jb2 = (tid >> 4) * 4;   // uv mapping
    #pragma unroll
    for (int tt = 0; tt < 2; ++tt) {
        const int t = h * 2 + tt;
        if (tt) __syncthreads();   // protect x_smT/buf before restage
        const float4* x4 = (const float4*)(x + ((size_t)b * II + (size_t)t * ITILE) * KK);
        #pragma unroll
        for (int idx = tid; idx < ITILE * KK / 4; idx += 256) {
            const int i = idx >> 4, kq = idx & 15;
            const float4 v = x4[idx];
            x_smT[kq * 4 + 0][i] = v.x; x_smT[kq * 4 + 1][i] = v.y;
            x_smT[kq * 4 + 2][i] = v.z; x_smT[kq * 4 + 3][i] = v.w;
        }
        __syncthreads();
        // uv[i][j] = sum_k x[i][k] wv[j][k]
        {
            float acc[4][4] = {};
            for (int k = 0; k < KK; ++k) {
                float xv[4], wvv[4];
                #pragma unroll
                for (int c = 0; c < 4; ++c) xv[c] = x_smT[k][ib + c];
                #pragma unroll
                for (int r = 0; r < 4; ++r) wvv[r] = wvs[jb2 + r][k];
                #pragma unroll
                for (int c = 0; c < 4; ++c)
                    #pragma unroll
                    for (int r = 0; r < 4; ++r)
                        acc[c][r] += xv[c] * wvv[r];
            }
            #pragma unroll
            for (int c = 0; c < 4; ++c)
                #pragma unroll
                for (int r = 0; r < 4; ++r)
                    buf[(ib + c) * 65 + jb2 + r] = acc[c][r];
        }
        __syncthreads();
        // softmax over j: wave w owns 16-j slice of row i=lane
        {
            const int i = tid & 63, w = tid >> 6, j0 = w * 16;
            float m = -1e30f;
            #pragma unroll
            for (int q = 0; q < 16; ++q) m = fmaxf(m, buf[i * 65 + j0 + q]);
            red[w][i] = m;
            __syncthreads();
            m = fmaxf(fmaxf(red[0][i], red[1][i]), fmaxf(red[2][i], red[3][i]));
            float s = 0.f;
            #pragma unroll
            for (int q = 0; q < 16; ++q) {
                const float e = __expf(buf[i * 65 + j0 + q] - m);
                buf[i * 65 + j0 + q] = e; s += e;
            }
            red[4 + w][i] = s;
            __syncthreads();
            const float inv = 1.f / (red[4][i] + red[5][i] + red[6][i] + red[7][i]);
            #pragma unroll
            for (int q = 0; q < 16; ++q) buf[i * 65 + j0 + q] *= inv;   // now c[i][j]
        }
        __syncthreads();
        // yacc[j][k] += sum_i c[i][j] x[i][k]
        for (int i = 0; i < ITILE; ++i) {
            float cv[4], xv[4];
            #pragma unroll
            for (int r = 0; r < 4; ++r) cv[r] = buf[i * 65 + jb + r];
            #pragma unroll
            for (int c = 0; c < 4; ++c) xv[c] = x_smT[kb + c][i];
            #pragma unroll
            for (int r = 0; r < 4; ++r)
                #pragma unroll
                for (int c = 0; c < 4; ++c)
                    yacc[r][c] += cv[r] * xv[c];
        }
    }
    float* yp = ypout + (size_t)(b * NP + h) * JJ * KK;
    #pragma unroll
    for (int r = 0; r < 4; ++r)
        *(float4*)&yp[(jb + r) * KK + kb] =
            make_float4(yacc[r][0], yacc[r][1], yacc[r][2], yacc[r][3]);
}

// ---------------------------------------------------------------------------
// K4: final caps. grid 64 = (b, g of 16 j): y3 = reduce(ypart), out = squash(W·y3).
// ---------------------------------------------------------------------------
__global__ __launch_bounds__(256) void final_caps(const float* __restrict__ W,
                                                  const float* __restrict__ ypart,
                                                  float* __restrict__ out) {
    const int b = blockIdx.x >> 2, g = blockIdx.x & 3;
    const int tid = threadIdx.x;
    __shared__ float y3[16][68];
    for (int e = tid; e < 16 * KK; e += 256) {
        const int l = e >> 6, k = e & 63;
        const int j = g * 16 + l;
        const float* p = ypart + ((size_t)(b * NP) * JJ + j) * KK + k;
        float a = 0.f;
        #pragma unroll
        for (int pp = 0; pp < NP; ++pp) a += p[(size_t)pp * JJ * KK];
        y3[l][k] = a;
    }
    __syncthreads();
    const int l = tid >> 4, dl = tid & 15;   // 16 threads per j
    const int j = g * 16 + l;
    const float4* yr = (const float4*)&y3[l][0];
    float sv[2]; float ss = 0.f;
    #pragma unroll
    for (int hh = 0; hh < 2; ++hh) {
        const int d = dl + hh * 16;
        const float4* Wr = (const float4*)(W + ((size_t)j * DD + d) * KK);
        float a = 0.f;
        #pragma unroll
        for (int q = 0; q < 16; ++q) {
            const float4 wq = Wr[q]; const float4 yq = yr[q];
            a += wq.x * yq.x + wq.y * yq.y + wq.z * yq.z + wq.w * yq.w;
        }
        sv[hh] = a; ss += a * a;
    }
    ss += __shfl_xor(ss, 1); ss += __shfl_xor(ss, 2);
    ss += __shfl_xor(ss, 4); ss += __shfl_xor(ss, 8);   // 16-lane group shares j
    const float f = ss / ((1.f + ss) * (sqrtf(ss) + 1e-8f));
    out[((size_t)b * JJ + j) * DD + dl]      = sv[0] * f;
    out[((size_t)b * JJ + j) * DD + dl + 16] = sv[1] * f;
}

// ---------------------------------------------------------------------------
// Workspace (floats): ybarp[8192] | v1g[32768] | ypA[1048576] | ypB[1048576]
// (~8.5 MB). Every buffer fully written before read; no memset, no atomics.
// ---------------------------------------------------------------------------
extern "C" void kernel_launch(void* const* d_in, const int* in_sizes, int n_in,
                              void* d_out, int out_size, void* d_ws, size_t ws_size,
                              hipStream_t stream) {
    const float* x = (const float*)d_in[0];
    const float* W = (const float*)d_in[1];
    float* out = (float*)d_out;
    float* ws = (float*)d_ws;

    float* ybarp = ws;                        // 8192
    float* v1g   = ws + 8192;                 // 32768
    float* ypA   = ws + 8192 + 32768;         // 1048576
    float* ypB   = ypA + 1048576;             // 1048576

    ybar_kernel<<<dim3(BB * YQ), 256, 0, stream>>>(x, ybarp);
    route_caps<1><<<dim3(BB * HB), 256, 0, stream>>>(x, W, ybarp, nullptr, v1g, ypA);
    route_caps<2><<<dim3(BB * HB), 256, 0, stream>>>(x, W, ybarp, ypA, v1g, ypB);
    final_caps<<<dim3(BB * 4), 256, 0, stream>>>(W, ypB, out);
}

// Round 7
// 138.426 us; speedup vs baseline: 2.9652x; 1.1906x over previous
//
#include <hip/hip_runtime.h>
#include <math.h>

// RoutingCapsules — B=16, I=2048, K=64, J=64, D=32, 3 routing iters.
//   s[b,j,d]  = sum_k W[j,d,k] y[b,j,k],    y[b,j,k]  = sum_i c[b,j,i] x[b,i,k]
//   uv[b,j,i] = sum_k x[b,i,k] wv[b,j,k],   wv[b,j,k] = sum_d W[j,d,k] v[b,j,d]
// Iter-1 c uniform -> y1 = ybar[b,k]. Logits linear in wv: b2 = x·(wv1+wv2).
//
// R6 post-mortem: fused redundant caps read W uncoalesced (per-lane rows) ->
// 62us kernels. Constant ~43us d_ws poison-fill sits inside dur_us; graph node
// overhead is only ~2us -> separate small kernels are cheap. This round:
// 6 plain launches; caps kernels use coalesced 4-rows-per-wave W streaming;
// route kernel uses stride-68 b128 LDS tiles (conflict-free) at 2 blocks/CU.

#define BB 16
#define II 2048
#define KK 64
#define JJ 64
#define DD 32
#define ITILE 64
#define NT 32    // route i-tiles per batch = ypart partials
#define YQ 16    // ybar chunks per batch

// ---------------------------------------------------------------------------
// K1: ybar partials. grid 256 = (b, q of 128 i).
// ---------------------------------------------------------------------------
__global__ __launch_bounds__(256) void ybar_kernel(const float* __restrict__ x,
                                                   float* __restrict__ ybarp) {
    const int b = blockIdx.x >> 4, q = blockIdx.x & 15;
    const int tid = threadIdx.x, k = tid & 63, r = tid >> 6;
    const float* xp = x + ((size_t)b * II + q * 128) * KK + k;
    float acc = 0.f;
    #pragma unroll 8
    for (int i = r; i < 128; i += 4) acc += xp[(size_t)i * KK];
    __shared__ float sm[256];
    sm[tid] = acc;
    __syncthreads();
    if (tid < 64)
        ybarp[(b * YQ + q) * KK + tid] =
            (sm[tid] + sm[tid + 64] + sm[tid + 128] + sm[tid + 192]) * (1.f / 64.f);
}

// ---------------------------------------------------------------------------
// caps kernel: grid 64 = (b, g of 16 j). Coalesced W streaming:
//  phase A: s[jl,d] = W[j,d,:]·y  — 4 (j,d)-rows per wave float4-instr,
//           16-lane shfl reduce (wave w owns rows [w*128,w*128+128) -> jl in [4w,4w+4))
//  f[jl] from ss;  phase B: wv[j,k] = f * sum_d W[j,d,k] s[j,d]
//  MODE 0: y = reduced ybarp (j-indep)       -> dst = wv1
//  MODE 1: y = reduced ypart[j]; + wv1[j,k]  -> dst = wvT
//  MODE 2: y = reduced ypart[j]; out = f*s   -> dst = out
// ---------------------------------------------------------------------------
template <int MODE>
__global__ __launch_bounds__(256) void caps_kernel(
    const float* __restrict__ W, const float* __restrict__ ybarp,
    const float* __restrict__ ypin, const float* __restrict__ wv1,
    float* __restrict__ dst)
{
    const int b = blockIdx.x >> 2, g = blockIdx.x & 3;
    const int j0 = g * 16;
    const int tid = threadIdx.x, w = tid >> 6, l = tid & 63;

    __shared__ float y_sm[16][KK + 4];   // MODE!=0 per-j rows (row 0 used for MODE 0)
    __shared__ float s_sm[512];          // s[jl*32+d]
    __shared__ float f_sm[16];

    // ---- gather y ----
    if (MODE == 0) {
        if (tid < KK) {
            float a = 0.f;
            #pragma unroll
            for (int q = 0; q < YQ; ++q) a += ybarp[(b * YQ + q) * KK + tid];
            y_sm[0][tid] = a;
        }
    } else {
        for (int e = tid; e < 16 * KK; e += 256) {
            const int jl = e >> 6, k = e & 63;
            const float* p = ypin + ((size_t)b * NT * JJ + (j0 + jl)) * KK + k;
            float a = 0.f;
            #pragma unroll 8
            for (int t = 0; t < NT; ++t) a += p[(size_t)t * JJ * KK];
            y_sm[jl][k] = a;
        }
    }
    __syncthreads();

    // ---- phase A: 512 rows (jl,d); wave w owns rows [w*128, w*128+128) ----
    {
        const int k4 = l & 15, rsub = l >> 4;
        float4 yv0;
        if (MODE == 0) yv0 = *(const float4*)&y_sm[0][k4 * 4];
        #pragma unroll 4
        for (int it = 0; it < 32; ++it) {
            const int r = w * 128 + it * 4 + rsub;      // jl = r>>5, d = r&31
            const int jg = j0 + (r >> 5);
            const float4 wq = ((const float4*)W)[((size_t)jg * DD + (r & 31)) * 16 + k4];
            const float4 yv = (MODE == 0) ? yv0 : *(const float4*)&y_sm[r >> 5][k4 * 4];
            float p = wq.x * yv.x + wq.y * yv.y + wq.z * yv.z + wq.w * yv.w;
            p += __shfl_xor(p, 1); p += __shfl_xor(p, 2);
            p += __shfl_xor(p, 4); p += __shfl_xor(p, 8);
            if (k4 == 0) s_sm[r] = p;
        }
    }
    // ---- squash factor per jl (wave-local: jl = tid>>4 in [4w,4w+4)) ----
    {
        const int jl = tid >> 4, dh = tid & 15;
        const float a0 = s_sm[jl * 32 + dh], a1 = s_sm[jl * 32 + 16 + dh];
        float ss = a0 * a0 + a1 * a1;
        ss += __shfl_xor(ss, 1); ss += __shfl_xor(ss, 2);
        ss += __shfl_xor(ss, 4); ss += __shfl_xor(ss, 8);
        if (dh == 0) f_sm[jl] = ss / ((1.f + ss) * (sqrtf(ss) + 1e-8f));
    }

    if (MODE == 2) {
        __syncthreads();
        #pragma unroll
        for (int rep = 0; rep < 2; ++rep) {
            const int idx = rep * 256 + tid;
            const int jl = idx >> 5, d = idx & 31;
            dst[((size_t)b * JJ + (j0 + jl)) * DD + d] = f_sm[jl] * s_sm[jl * 32 + d];
        }
        return;
    }

    // ---- phase B: wv[j,k] = f * sum_d W[j,d,k] s[j,d]; wave w owns jl in [4w,4w+4) ----
    {
        const int k4 = l & 15, dg = l >> 4;
        #pragma unroll
        for (int jj = 0; jj < 4; ++jj) {
            const int jl = w * 4 + jj, jg = j0 + jl;
            float4 acc = make_float4(0.f, 0.f, 0.f, 0.f);
            #pragma unroll
            for (int dq = 0; dq < 8; ++dq) {
                const int d = dq * 4 + dg;
                const float sd = s_sm[jl * 32 + d];
                const float4 wq = ((const float4*)W)[((size_t)jg * DD + d) * 16 + k4];
                acc.x += wq.x * sd; acc.y += wq.y * sd;
                acc.z += wq.z * sd; acc.w += wq.w * sd;
            }
            acc.x += __shfl_xor(acc.x, 16); acc.x += __shfl_xor(acc.x, 32);
            acc.y += __shfl_xor(acc.y, 16); acc.y += __shfl_xor(acc.y, 32);
            acc.z += __shfl_xor(acc.z, 16); acc.z += __shfl_xor(acc.z, 32);
            acc.w += __shfl_xor(acc.w, 16); acc.w += __shfl_xor(acc.w, 32);
            if (dg == 0) {
                const float fj = f_sm[jl];
                float4 o = make_float4(acc.x * fj, acc.y * fj, acc.z * fj, acc.w * fj);
                if (MODE == 1) {
                    const float4 base =
                        ((const float4*)&wv1[((size_t)b * JJ + jg) * KK])[k4];
                    o.x += base.x; o.y += base.y; o.z += base.z; o.w += base.w;
                }
                ((float4*)&dst[((size_t)b * JJ + jg) * KK])[k4] = o;
            }
        }
    }
}

// ---------------------------------------------------------------------------
// route kernel: grid 512 = (b, t). uv = x·wv^T, softmax_j -> c, ypart = c^T·x.
// All LDS tiles stride-68, b128 accesses; 4x4-blocked inner loops.
// 53.3 KB LDS -> 2 blocks/CU.
// ---------------------------------------------------------------------------
__global__ __launch_bounds__(256, 2) void route_kernel(
    const float* __restrict__ x, const float* __restrict__ wvg,
    float* __restrict__ ypart)
{
    const int b = blockIdx.x >> 5;
    const int t = blockIdx.x & 31;
    const int tid = threadIdx.x;

    __shared__ float x_smT[KK][ITILE + 4];   // [k][i]
    __shared__ float wvs[JJ][KK + 4];        // [j][k]
    __shared__ float cbuf[ITILE][JJ + 4];    // [i][j] : uv -> c
    __shared__ float red[8][72];

    // stage wv rows (direct f4) and x tile (transposed)
    const float4* wv4 = (const float4*)(wvg + (size_t)b * JJ * KK);
    #pragma unroll
    for (int idx = tid; idx < JJ * KK / 4; idx += 256)
        *(float4*)&wvs[idx >> 4][(idx & 15) * 4] = wv4[idx];
    const float4* x4 = (const float4*)(x + ((size_t)b * II + (size_t)t * ITILE) * KK);
    #pragma unroll
    for (int idx = tid; idx < ITILE * KK / 4; idx += 256) {
        const int i = idx >> 4, k4 = idx & 15;
        const float4 v = x4[idx];
        x_smT[k4 * 4 + 0][i] = v.x; x_smT[k4 * 4 + 1][i] = v.y;
        x_smT[k4 * 4 + 2][i] = v.z; x_smT[k4 * 4 + 3][i] = v.w;
    }
    __syncthreads();

    // ---- uv GEMM: acc[c:i][r:j], k blocked by 4, all b128 ----
    {
        const int ib = (tid & 15) * 4, jb = (tid >> 4) * 4;
        float acc[4][4] = {};
        #pragma unroll 4
        for (int k4 = 0; k4 < 16; ++k4) {
            float xr[4][4], wr[4][4];
            #pragma unroll
            for (int kk = 0; kk < 4; ++kk) {
                const float4 v = *(const float4*)&x_smT[k4 * 4 + kk][ib];
                xr[kk][0] = v.x; xr[kk][1] = v.y; xr[kk][2] = v.z; xr[kk][3] = v.w;
            }
            #pragma unroll
            for (int r = 0; r < 4; ++r) {
                const float4 v = *(const float4*)&wvs[jb + r][k4 * 4];
                wr[r][0] = v.x; wr[r][1] = v.y; wr[r][2] = v.z; wr[r][3] = v.w;
            }
            #pragma unroll
            for (int kk = 0; kk < 4; ++kk)
                #pragma unroll
                for (int c = 0; c < 4; ++c)
                    #pragma unroll
                    for (int r = 0; r < 4; ++r)
                        acc[c][r] += xr[kk][c] * wr[r][kk];
        }
        #pragma unroll
        for (int c = 0; c < 4; ++c)
            *(float4*)&cbuf[ib + c][jb] =
                make_float4(acc[c][0], acc[c][1], acc[c][2], acc[c][3]);
    }
    __syncthreads();

    // ---- softmax over j: wave wv_ owns 16-j slice of row i; e kept in regs ----
    {
        const int i = tid & 63, wv_ = tid >> 6, j0 = wv_ * 16;
        float u[16];
        #pragma unroll
        for (int q = 0; q < 4; ++q) {
            const float4 v = *(const float4*)&cbuf[i][j0 + q * 4];
            u[q*4+0] = v.x; u[q*4+1] = v.y; u[q*4+2] = v.z; u[q*4+3] = v.w;
        }
        float m = -1e30f;
        #pragma unroll
        for (int q = 0; q < 16; ++q) m = fmaxf(m, u[q]);
        red[wv_][i] = m;
        __syncthreads();
        m = fmaxf(fmaxf(red[0][i], red[1][i]), fmaxf(red[2][i], red[3][i]));
        float s = 0.f;
        #pragma unroll
        for (int q = 0; q < 16; ++q) { u[q] = __expf(u[q] - m); s += u[q]; }
        red[4 + wv_][i] = s;
        __syncthreads();
        const float inv = 1.f / (red[4][i] + red[5][i] + red[6][i] + red[7][i]);
        #pragma unroll
        for (int q = 0; q < 4; ++q)
            *(float4*)&cbuf[i][j0 + q * 4] =
                make_float4(u[q*4+0]*inv, u[q*4+1]*inv, u[q*4+2]*inv, u[q*4+3]*inv);
    }
    __syncthreads();

    // ---- ypart GEMM: acc[r:j][c:k], i blocked by 4, all b128 ----
    {
        const int jb = (tid & 15) * 4, kb = (tid >> 4) * 4;
        float acc[4][4] = {};
        #pragma unroll 4
        for (int i4 = 0; i4 < 16; ++i4) {
            float cr[4][4], xr[4][4];   // cr[ii][r], xr[c][ii]
            #pragma unroll
            for (int ii = 0; ii < 4; ++ii) {
                const float4 v = *(const float4*)&cbuf[i4 * 4 + ii][jb];
                cr[ii][0] = v.x; cr[ii][1] = v.y; cr[ii][2] = v.z; cr[ii][3] = v.w;
            }
            #pragma unroll
            for (int c = 0; c < 4; ++c) {
                const float4 v = *(const float4*)&x_smT[kb + c][i4 * 4];
                xr[c][0] = v.x; xr[c][1] = v.y; xr[c][2] = v.z; xr[c][3] = v.w;
            }
            #pragma unroll
            for (int ii = 0; ii < 4; ++ii)
                #pragma unroll
                for (int r = 0; r < 4; ++r)
                    #pragma unroll
                    for (int c = 0; c < 4; ++c)
                        acc[r][c] += cr[ii][r] * xr[c][ii];
        }
        float* yp = ypart + ((size_t)b * NT + t) * JJ * KK;
        #pragma unroll
        for (int r = 0; r < 4; ++r)
            *(float4*)&yp[(jb + r) * KK + kb] =
                make_float4(acc[r][0], acc[r][1], acc[r][2], acc[r][3]);
    }
}

// ---------------------------------------------------------------------------
// Workspace (floats): ybarp[16384] | wv1[65536] | wvT[65536] | ypA[2097152] |
// ypB[2097152]  (~17.3 MB). No memset, no atomics, no fences.
// ---------------------------------------------------------------------------
extern "C" void kernel_launch(void* const* d_in, const int* in_sizes, int n_in,
                              void* d_out, int out_size, void* d_ws, size_t ws_size,
                              hipStream_t stream) {
    const float* x = (const float*)d_in[0];
    const float* W = (const float*)d_in[1];
    float* out = (float*)d_out;
    float* ws = (float*)d_ws;

    float* ybarp = ws;                  // 16384
    float* wv1   = ybarp + 16384;       // 65536
    float* wvT   = wv1 + 65536;         // 65536
    float* ypA   = wvT + 65536;         // 2097152
    float* ypB   = ypA + 2097152;       // 2097152

    ybar_kernel<<<dim3(BB * YQ), 256, 0, stream>>>(x, ybarp);
    caps_kernel<0><<<dim3(BB * 4), 256, 0, stream>>>(W, ybarp, nullptr, nullptr, wv1);
    route_kernel<<<dim3(BB * NT), 256, 0, stream>>>(x, wv1, ypA);
    caps_kernel<1><<<dim3(BB * 4), 256, 0, stream>>>(W, ybarp, ypA, wv1, wvT);
    route_kernel<<<dim3(BB * NT), 256, 0, stream>>>(x, wvT, ypB);
    caps_kernel<2><<<dim3(BB * 4), 256, 0, stream>>>(W, ybarp, ypB, nullptr, out);
}